// Round 16
// baseline (302.570 us; speedup 1.0000x reference)
//
#include <hip/hip_runtime.h>
#include <hip/hip_bf16.h>
#include <math.h>

// B=8192, D=512, V=64, E=8, hidden (1024,512,256)
// Round 16: R15 (single-f16 x single-f16, 128x128, 64-k steps, 4 blk/CU)
// + swapped-operand MFMA => lane holds 4 consecutive C-cols => packed
// 8B/16B epilogue stores (16 instrs vs 64 scalar), 8-shuffle mode-2 reduce,
// and gate3_softmax+combine fused into one kernel.

typedef _Float16 f16x8 __attribute__((ext_vector_type(8)));
typedef float f32x4 __attribute__((ext_vector_type(4)));
typedef ushort ushort4v __attribute__((ext_vector_type(4)));

#define AS1 __attribute__((address_space(1)))
#define AS3 __attribute__((address_space(3)))
#define SCHED0 __builtin_amdgcn_sched_barrier(0)
#define SBAR __builtin_amdgcn_s_barrier()

__device__ __forceinline__ ushort h2u(_Float16 h){
  union { _Float16 h; ushort u; } v; v.h = h; return v.u;
}
__device__ __forceinline__ float elu_f(float x){
  return x > 0.f ? x : __expf(x) - 1.f;
}

// ---- unified prep: activations f32 -> single f16 (RN) ----
struct AJob { const float* X; ushort* A; int total; };
__global__ void prep_act_all(AJob j0, AJob j1, int t0){
  int i = blockIdx.x * 256 + threadIdx.x;
  AJob J; int idx;
  if (i < t0){ J = j0; idx = i; }
  else { J = j1; idx = i - t0; if (idx >= J.total) return; }
  J.A[idx] = h2u((_Float16)J.X[idx]);
}

// ---- unified prep: weights f32 [E][K][N] -> [E][N][K] single f16 ----
struct WJob { const float* W; ushort* Bt; int K, N, nb, nk, blkStart; };
struct WJobs { WJob j[6]; int njobs; };
__global__ void prep_w_all(WJobs jobs){
  __shared__ float tile[32][33];
  int b = blockIdx.x;
  int ji = 0;
  while (ji + 1 < jobs.njobs && b >= jobs.j[ji + 1].blkStart) ji++;
  WJob J = jobs.j[ji];
  int rem = b - J.blkStart;
  int x = rem % J.nb; rem /= J.nb;
  int y = rem % J.nk; int e = rem / J.nk;
  const float* w = J.W + (size_t)e * J.K * J.N;
  ushort* bt = J.Bt + (size_t)e * J.N * J.K;
  int n0 = x * 32, k0 = y * 32;
  for (int i = threadIdx.y; i < 32; i += 8)
    tile[i][threadIdx.x] = w[(size_t)(k0 + i) * J.N + n0 + threadIdx.x];
  __syncthreads();
  for (int jj = threadIdx.y; jj < 32; jj += 8){
    float v = tile[threadIdx.x][jj];
    bt[(size_t)(n0 + jj) * J.K + k0 + threadIdx.x] = h2u((_Float16)v);
  }
}

// ---- descriptor-batched 128x128 GEMM, single-f16, 64-k steps ----
// Swapped-operand MFMA: acc[m][n] = mfma(bv[n], av[m], acc) =>
//   C-row = rowBase + wr*64 + m*16 + (lane&15)
//   C-col = colBase + wc*64 + n*16 + (lane>>4)*4 + r   (r = 0..3 consecutive)
// mode 0: C = f16 [M][N]; mode 1: C = f32 [M][N];
// mode 2: no C — ret[bx][row][eidx] = partial sum_col elu(acc+bias)*w3
struct Slice {
  const ushort* A; const ushort* Bt; const float* bias; void* C;
  const float* w3; const float* rbp; float* ret;
  int N, K, log2gx, mode, blkStart, eidx;
};
struct SliceArr { Slice s[9]; int nz; };

__global__ __launch_bounds__(256, 3) void gemm8p(SliceArr args){
  // A,B tiles [128][64] f16 (16KB each), cols = k 0..63, XOR-swizzled
  __shared__ __align__(16) ushort As[128][64];
  __shared__ __align__(16) ushort Bs[128][64];
  __shared__ float red[2][128];

  // XCD-chunked bijective swizzle (grids here are multiples of 8)
  const int nwg  = gridDim.x;
  const int orig = blockIdx.x;
  const int wg   = (orig & 7) * (nwg >> 3) + (orig >> 3);

  int z = 0;
  while (z + 1 < args.nz && wg >= args.s[z + 1].blkStart) z++;
  const Slice sl = args.s[z];
  const int rem = wg - sl.blkStart;
  const int gxm = (1 << sl.log2gx) - 1;
  const int bx  = rem & gxm;
  const int by  = rem >> sl.log2gx;

  const ushort* __restrict__ Ag = sl.A;
  const ushort* __restrict__ Bg = sl.Bt;
  const int K = sl.K;

  const int tid  = threadIdx.x;
  const int lane = tid & 63;
  const int wave = tid >> 6;                    // 0..3
  const int wr = wave >> 1;                     // 0..1 : rows wr*64..+63
  const int wc = wave & 1;                      // 0..1 : cols wc*64..+63
  const int rowBase = by * 128;
  const int colBase = bx * 128;
  const int KB = K >> 6;                        // 64-k steps
  const int lr = lane & 15;
  const int lk = (lane >> 4) << 3;
  const int swzR = (lr & 7) << 3;

  // staging constants: 4 instrs per tile; rows j*32+rS, source col swizzled
  const int rS = tid >> 3;                      // 0..31
  const int cS = ((tid & 7) << 3) ^ ((rS & 7) << 3);

  // stage A (16KB) + B (16KB) of 64-k step kt (8 instrs/thread)
  auto stage = [&](int kt){
    int tt = (kt < KB) ? kt : (KB - 1);         // clamp: dead-but-safe
    int kc = (tt << 6) + cS;
    {
      char* lb = (char*)&As[0][0];
      #pragma unroll
      for (int j = 0; j < 4; j++){
        const ushort* src = Ag + (size_t)(rowBase + j * 32 + rS) * (size_t)K + kc;
        __builtin_amdgcn_global_load_lds((const AS1 void*)src,
                                         (AS3 void*)(lb + j * 4096 + tid * 16), 16, 0, 0);
      }
    }
    {
      char* lb = (char*)&Bs[0][0];
      #pragma unroll
      for (int j = 0; j < 4; j++){
        const ushort* src = Bg + (size_t)(colBase + j * 32 + rS) * (size_t)K + kc;
        __builtin_amdgcn_global_load_lds((const AS1 void*)src,
                                         (AS3 void*)(lb + j * 4096 + tid * 16), 16, 0, 0);
      }
    }
  };

  f16x8 av[4], bv[4];
  auto readKs = [&](int ks){
    int kc = (ks << 5) + lk;                    // 0..63
    #pragma unroll
    for (int n = 0; n < 4; n++)
      bv[n] = *(const f16x8*)&Bs[wc * 64 + n * 16 + lr][kc ^ swzR];
    #pragma unroll
    for (int m = 0; m < 4; m++)
      av[m] = *(const f16x8*)&As[wr * 64 + m * 16 + lr][kc ^ swzR];
  };

  f32x4 acc[4][4];
  #pragma unroll
  for (int m = 0; m < 4; m++)
    #pragma unroll
    for (int n = 0; n < 4; n++)
      acc[m][n] = (f32x4){0.f, 0.f, 0.f, 0.f};

  auto mfmaC = [&](){
    #pragma unroll
    for (int m = 0; m < 4; m++)
      #pragma unroll
      for (int n = 0; n < 4; n++)
        acc[m][n] = __builtin_amdgcn_mfma_f32_16x16x32_f16(bv[n], av[m], acc[m][n], 0, 0, 0);
  };

  // prologue
  stage(0);

  for (int t = 0; t < KB; ++t){
    asm volatile("s_waitcnt vmcnt(0)" ::: "memory");  // tile t landed
    SCHED0; SBAR; SCHED0;
    readKs(0);
    asm volatile("s_waitcnt lgkmcnt(0)" ::: "memory"); SCHED0;
    __builtin_amdgcn_s_setprio(1); mfmaC(); __builtin_amdgcn_s_setprio(0);
    SCHED0;
    readKs(1);
    asm volatile("s_waitcnt lgkmcnt(0)" ::: "memory"); SCHED0;
    SBAR; SCHED0;                                     // all reads done blockwide
    stage(t + 1); SCHED0;                             // DMA rides under MFMA
    __builtin_amdgcn_s_setprio(1); mfmaC(); __builtin_amdgcn_s_setprio(0);
    SCHED0;
  }
  asm volatile("s_waitcnt vmcnt(0)" ::: "memory");    // drain dead last stage

  // ---- epilogue (swapped layout) ----
  const int rowL = lane & 15;                   // row within 16-frag
  const int c4  = (lane >> 4) << 2;             // col group 0,4,8,12

  if (sl.mode == 2){
    __syncthreads();
    #pragma unroll
    for (int m = 0; m < 4; m++){
      float s = 0.f;
      #pragma unroll
      for (int n = 0; n < 4; n++){
        int col0 = colBase + wc * 64 + n * 16 + c4;
        f32x4 bv4 = *(const f32x4*)&sl.bias[col0];
        f32x4 wv4 = *(const f32x4*)&sl.w3[col0];
        #pragma unroll
        for (int r = 0; r < 4; r++)
          s += elu_f(acc[m][n][r] + bv4[r]) * wv4[r];
      }
      s += __shfl_xor(s, 16, 64);
      s += __shfl_xor(s, 32, 64);
      if (lane < 16)
        red[wc][wr * 64 + m * 16 + rowL] = s;
    }
    __syncthreads();
    if (tid < 128){
      float s2 = red[0][tid] + red[1][tid];
      sl.ret[((size_t)bx * 8192 + rowBase + tid) * 8 + sl.eidx] = s2;  // bias in combine
    }
    return;
  }

  const int N = sl.N;
  #pragma unroll
  for (int m = 0; m < 4; m++){
    int row = rowBase + wr * 64 + m * 16 + rowL;
    #pragma unroll
    for (int n = 0; n < 4; n++){
      int col0 = colBase + wc * 64 + n * 16 + c4;
      f32x4 bv4 = *(const f32x4*)&sl.bias[col0];
      float v0 = elu_f(acc[m][n][0] + bv4[0]);
      float v1 = elu_f(acc[m][n][1] + bv4[1]);
      float v2 = elu_f(acc[m][n][2] + bv4[2]);
      float v3 = elu_f(acc[m][n][3] + bv4[3]);
      if (sl.mode == 0){
        ushort4v pk = { h2u((_Float16)v0), h2u((_Float16)v1),
                        h2u((_Float16)v2), h2u((_Float16)v3) };   // RN
        *(ushort4v*)((ushort*)sl.C + (size_t)row * N + col0) = pk;
      } else {
        f32x4 pv = { v0, v1, v2, v3 };
        *(f32x4*)((float*)sl.C + (size_t)row * N + col0) = pv;
      }
    }
  }
}

// ---- fused gate final layer + softmax + combine ----
__global__ void gate3_combine(const float* __restrict__ g2, const float* __restrict__ gw3,
                              const float* __restrict__ gb3, const float* __restrict__ ret2,
                              const float* __restrict__ eb3, float* __restrict__ out){
  int row = blockIdx.x * 4 + (threadIdx.x >> 6);
  int lane = threadIdx.x & 63;
  const float* g = g2 + (size_t)row * 256;
  float p[8];
  #pragma unroll
  for (int j = 0; j < 8; j++) p[j] = 0.f;
  for (int k = lane; k < 256; k += 64){
    float x = g[k];
    #pragma unroll
    for (int j = 0; j < 8; j++) p[j] += x * gw3[k * 8 + j];
  }
  #pragma unroll
  for (int j = 0; j < 8; j++){
    #pragma unroll
    for (int s = 32; s > 0; s >>= 1) p[j] += __shfl_xor(p[j], s, 64);
  }
  if (lane == 0){
    float mx = -1e30f;
    #pragma unroll
    for (int j = 0; j < 8; j++){ p[j] += gb3[j]; mx = fmaxf(mx, p[j]); }
    float sum = 0.f;
    #pragma unroll
    for (int j = 0; j < 8; j++){ p[j] = expf(p[j] - mx); sum += p[j]; }
    float inv = 1.f / sum;
    float s = 0.f;
    #pragma unroll
    for (int j = 0; j < 8; j++){
      float r = ret2[(size_t)row * 8 + j] + ret2[65536 + (size_t)row * 8 + j] + eb3[j];
      s += p[j] * inv * r;
    }
    out[row] = s;
  }
}

extern "C" void kernel_launch(void* const* d_in, const int* in_sizes, int n_in,
                              void* d_out, int out_size, void* d_ws, size_t ws_size,
                              hipStream_t stream){
  const float* obs  = (const float*)d_in[0];
  const float* code = (const float*)d_in[1];
  const float* ew0  = (const float*)d_in[2];
  const float* eb0  = (const float*)d_in[3];
  const float* ew1  = (const float*)d_in[4];
  const float* eb1  = (const float*)d_in[5];
  const float* ew2  = (const float*)d_in[6];
  const float* eb2  = (const float*)d_in[7];
  const float* ew3  = (const float*)d_in[8];
  const float* eb3  = (const float*)d_in[9];
  const float* gw0  = (const float*)d_in[10];
  const float* gb0  = (const float*)d_in[11];
  const float* gw1  = (const float*)d_in[12];
  const float* gb1  = (const float*)d_in[13];
  const float* gw2  = (const float*)d_in[14];
  const float* gb2  = (const float*)d_in[15];
  const float* gw3  = (const float*)d_in[16];
  const float* gb3  = (const float*)d_in[17];
  (void)in_sizes; (void)n_in; (void)out_size;

  char* ws = (char*)d_ws;
  size_t off = 0;
  auto alloc = [&](size_t bytes) -> void* {
    void* p = ws + off;
    off += (bytes + 255) & ~(size_t)255;
    return p;
  };
  ushort* A_obs  = (ushort*)alloc(8192ull * 512 * 2);      // [8192][512] f16
  ushort* A_code = (ushort*)alloc(8192ull * 64 * 2);       // [8192][64] f16
  ushort* B_ew0  = (ushort*)alloc(8ull * 1024 * 512 * 2);  // [8][1024][512] f16
  ushort* B_ew1  = (ushort*)alloc(8ull * 512 * 1024 * 2);
  ushort* B_ew2  = (ushort*)alloc(8ull * 256 * 512 * 2);
  ushort* B_gw0  = (ushort*)alloc(1024ull * 64 * 2);
  ushort* B_gw1  = (ushort*)alloc(512ull * 1024 * 2);
  ushort* B_gw2  = (ushort*)alloc(256ull * 512 * 2);
  float*  ret2   = (float*)alloc(2ull * 8192 * 8 * 4);
  const size_t fixed = off;

  const size_t sl0b = 8192ull * 1024 * 2;   // h0 single f16 (16.8MB)
  const size_t sl1b = 8192ull * 512 * 2;    // h1 single f16 (8.4MB)
  const size_t pairB = sl0b + sl1b;

  int G = 0;
  {
    const int cand[5] = {8, 4, 3, 2, 1};
    for (int ci = 0; ci < 5; ci++)
      if (fixed + (size_t)(cand[ci] + 1) * pairB <= ws_size){ G = cand[ci]; break; }
  }
  const bool gateFirst = (G == 0);
  const int ns = gateFirst ? 1 : (G + 1);
  ushort* h0buf = (ushort*)alloc((size_t)ns * sl0b);
  ushort* h1buf = (ushort*)alloc((size_t)ns * sl1b);
  const size_t sl0e = 8192ull * 1024;
  const size_t sl1e = 8192ull * 512;
  const int gsl = ns - 1;
  ushort* h0g = h0buf + (size_t)gsl * sl0e;
  ushort* h1g = h1buf + (size_t)gsl * sl1e;
  float*  h2g = (float*)h0g;                 // alias: h0g (16.8MB) >= h2 (8.4MB)

  // prep (2 dispatches)
  {
    AJob j0 = {obs,  A_obs,  8192 * 512};
    AJob j1 = {code, A_code, 8192 * 64};
    int t0 = 8192 * 512;
    prep_act_all<<<dim3((t0 + j1.total + 255) / 256), 256, 0, stream>>>(j0, j1, t0);

    WJobs wj; wj.njobs = 6;
    int bs = 0;
    auto addW = [&](int i, const float* W, ushort* Bt, int K, int N, int E){
      wj.j[i] = {W, Bt, K, N, N / 32, K / 32, bs};
      bs += E * (N / 32) * (K / 32);
    };
    addW(0, ew0, B_ew0, 512, 1024, 8);
    addW(1, ew1, B_ew1, 1024, 512, 8);
    addW(2, ew2, B_ew2, 512, 256, 8);
    addW(3, gw0, B_gw0, 64, 1024, 1);
    addW(4, gw1, B_gw1, 1024, 512, 1);
    addW(5, gw2, B_gw2, 512, 256, 1);
    prep_w_all<<<dim3(bs), dim3(32, 8), 0, stream>>>(wj);
  }

  // per-slice block counts at 128x128 tiles (gy = 64)
  const int NB0 = 8 * 64;    // L0: N=1024 -> 512
  const int NB1 = 4 * 64;    // L1: N=512  -> 256
  const int NB2 = 2 * 64;    // L2: N=256  -> 128

  auto runGroup = [&](int e0, int cnt, bool withGate){
    SliceArr sa; int nb;
    // L0
    nb = 0; sa.nz = cnt + (withGate ? 1 : 0);
    for (int i = 0; i < cnt; i++){ int e = e0 + i;
      sa.s[i] = {A_obs, B_ew0 + (size_t)e * 1024 * 512, eb0 + e * 1024,
                 h0buf + (size_t)i * sl0e, nullptr, nullptr, nullptr,
                 1024, 512, 3, 0, nb, 0};
      nb += NB0;
    }
    if (withGate){
      sa.s[cnt] = {A_code, B_gw0, gb0, h0g, nullptr, nullptr, nullptr,
                   1024, 64, 3, 0, nb, 0};
      nb += NB0;
    }
    for (int i = sa.nz; i < 9; i++) sa.s[i] = sa.s[0];
    gemm8p<<<dim3(nb), 256, 0, stream>>>(sa);
    // L1
    nb = 0;
    for (int i = 0; i < cnt; i++){ int e = e0 + i;
      sa.s[i] = {h0buf + (size_t)i * sl0e, B_ew1 + (size_t)e * 512 * 1024, eb1 + e * 512,
                 h1buf + (size_t)i * sl1e, nullptr, nullptr, nullptr,
                 512, 1024, 2, 0, nb, 0};
      nb += NB1;
    }
    if (withGate){
      sa.s[cnt] = {h0g, B_gw1, gb1, h1g, nullptr, nullptr, nullptr,
                   512, 1024, 2, 0, nb, 0};
      nb += NB1;
    }
    gemm8p<<<dim3(nb), 256, 0, stream>>>(sa);
    // L2: experts fused-returns partials (mode 2); gate f32 h2 (mode 1)
    nb = 0;
    for (int i = 0; i < cnt; i++){ int e = e0 + i;
      sa.s[i] = {h1buf + (size_t)i * sl1e, B_ew2 + (size_t)e * 256 * 512, eb2 + e * 256,
                 nullptr, ew3 + (size_t)e * 256, eb3 + e, ret2,
                 256, 512, 1, 2, nb, e};
      nb += NB2;
    }
    if (withGate){
      sa.s[cnt] = {h1g, B_gw2, gb2, h2g, nullptr, nullptr, nullptr,
                   256, 512, 1, 1, nb, 0};
      nb += NB2;
    }
    gemm8p<<<dim3(nb), 256, 0, stream>>>(sa);
  };

  if (gateFirst){
    SliceArr sa; sa.nz = 1;
    sa.s[0] = {A_code, B_gw0, gb0, h0g, nullptr, nullptr, nullptr, 1024, 64, 3, 0, 0, 0};
    for (int i = 1; i < 9; i++) sa.s[i] = sa.s[0];
    gemm8p<<<dim3(NB0), 256, 0, stream>>>(sa);
    sa.s[0] = {h0g, B_gw1, gb1, h1g, nullptr, nullptr, nullptr, 512, 1024, 2, 0, 0, 0};
    gemm8p<<<dim3(NB1), 256, 0, stream>>>(sa);
    sa.s[0] = {h1g, B_gw2, gb2, h2g, nullptr, nullptr, nullptr, 256, 512, 1, 1, 0, 0};
    gemm8p<<<dim3(NB2), 256, 0, stream>>>(sa);
    for (int e = 0; e < 8; e++) runGroup(e, 1, false);
  } else {
    bool first = true;
    for (int e0 = 0; e0 < 8; ){
      int cnt = (8 - e0 < G) ? (8 - e0) : G;
      runGroup(e0, cnt, first);
      first = false;
      e0 += cnt;
    }
  }

  gate3_combine<<<dim3(2048), 256, 0, stream>>>(h2g, gw3, gb3, ret2, eb3, (float*)d_out);
}

// Round 17
// 285.904 us; speedup vs baseline: 1.0583x; 1.0583x over previous
//
#include <hip/hip_runtime.h>
#include <hip/hip_bf16.h>
#include <math.h>

// B=8192, D=512, V=64, E=8, hidden (1024,512,256)
// Round 17: revert R16's swapped-operand epilogue (it scattered stores:
// 16 row-distinct 8B segments/instr vs R15's 4 coalesced 32B segments);
// keep R15's proven GEMM exactly + the fused gate3_softmax+combine kernel.
// gateFirst path gets a dedicated h2 buffer (combine now runs at the end).

typedef _Float16 f16x8 __attribute__((ext_vector_type(8)));
typedef float f32x4 __attribute__((ext_vector_type(4)));

#define AS1 __attribute__((address_space(1)))
#define AS3 __attribute__((address_space(3)))
#define SCHED0 __builtin_amdgcn_sched_barrier(0)
#define SBAR __builtin_amdgcn_s_barrier()

__device__ __forceinline__ ushort h2u(_Float16 h){
  union { _Float16 h; ushort u; } v; v.h = h; return v.u;
}
__device__ __forceinline__ float elu_f(float x){
  return x > 0.f ? x : __expf(x) - 1.f;
}

// ---- unified prep: activations f32 -> single f16 (RN) ----
struct AJob { const float* X; ushort* A; int total; };
__global__ void prep_act_all(AJob j0, AJob j1, int t0){
  int i = blockIdx.x * 256 + threadIdx.x;
  AJob J; int idx;
  if (i < t0){ J = j0; idx = i; }
  else { J = j1; idx = i - t0; if (idx >= J.total) return; }
  J.A[idx] = h2u((_Float16)J.X[idx]);
}

// ---- unified prep: weights f32 [E][K][N] -> [E][N][K] single f16 ----
struct WJob { const float* W; ushort* Bt; int K, N, nb, nk, blkStart; };
struct WJobs { WJob j[6]; int njobs; };
__global__ void prep_w_all(WJobs jobs){
  __shared__ float tile[32][33];
  int b = blockIdx.x;
  int ji = 0;
  while (ji + 1 < jobs.njobs && b >= jobs.j[ji + 1].blkStart) ji++;
  WJob J = jobs.j[ji];
  int rem = b - J.blkStart;
  int x = rem % J.nb; rem /= J.nb;
  int y = rem % J.nk; int e = rem / J.nk;
  const float* w = J.W + (size_t)e * J.K * J.N;
  ushort* bt = J.Bt + (size_t)e * J.N * J.K;
  int n0 = x * 32, k0 = y * 32;
  for (int i = threadIdx.y; i < 32; i += 8)
    tile[i][threadIdx.x] = w[(size_t)(k0 + i) * J.N + n0 + threadIdx.x];
  __syncthreads();
  for (int jj = threadIdx.y; jj < 32; jj += 8){
    float v = tile[threadIdx.x][jj];
    bt[(size_t)(n0 + jj) * J.K + k0 + threadIdx.x] = h2u((_Float16)v);
  }
}

// ---- descriptor-batched 128x128 GEMM, single-f16, 64-k steps ----
// mode 0: C = f16 [M][N]; mode 1: C = f32 [M][N];
// mode 2: no C — ret[bx][row][eidx] = partial sum_col elu(acc+bias)*w3
struct Slice {
  const ushort* A; const ushort* Bt; const float* bias; void* C;
  const float* w3; const float* rbp; float* ret;
  int N, K, log2gx, mode, blkStart, eidx;
};
struct SliceArr { Slice s[9]; int nz; };

__global__ __launch_bounds__(256, 3) void gemm8p(SliceArr args){
  // A,B tiles [128][64] f16 (16KB each), cols = k 0..63, XOR-swizzled
  __shared__ __align__(16) ushort As[128][64];
  __shared__ __align__(16) ushort Bs[128][64];
  __shared__ float red[2][128];

  // XCD-chunked bijective swizzle (grids here are multiples of 8)
  const int nwg  = gridDim.x;
  const int orig = blockIdx.x;
  const int wg   = (orig & 7) * (nwg >> 3) + (orig >> 3);

  int z = 0;
  while (z + 1 < args.nz && wg >= args.s[z + 1].blkStart) z++;
  const Slice sl = args.s[z];
  const int rem = wg - sl.blkStart;
  const int gxm = (1 << sl.log2gx) - 1;
  const int bx  = rem & gxm;
  const int by  = rem >> sl.log2gx;

  const ushort* __restrict__ Ag = sl.A;
  const ushort* __restrict__ Bg = sl.Bt;
  const int K = sl.K;

  const int tid  = threadIdx.x;
  const int lane = tid & 63;
  const int wave = tid >> 6;                    // 0..3
  const int wr = wave >> 1;                     // 0..1 : rows wr*64..+63
  const int wc = wave & 1;                      // 0..1 : cols wc*64..+63
  const int rowBase = by * 128;
  const int colBase = bx * 128;
  const int KB = K >> 6;                        // 64-k steps
  const int lr = lane & 15;
  const int lk = (lane >> 4) << 3;
  const int swzR = (lr & 7) << 3;

  // staging constants: 4 instrs per tile; rows j*32+rS, source col swizzled
  const int rS = tid >> 3;                      // 0..31
  const int cS = ((tid & 7) << 3) ^ ((rS & 7) << 3);

  // stage A (16KB) + B (16KB) of 64-k step kt (8 instrs/thread)
  auto stage = [&](int kt){
    int tt = (kt < KB) ? kt : (KB - 1);         // clamp: dead-but-safe
    int kc = (tt << 6) + cS;
    {
      char* lb = (char*)&As[0][0];
      #pragma unroll
      for (int j = 0; j < 4; j++){
        const ushort* src = Ag + (size_t)(rowBase + j * 32 + rS) * (size_t)K + kc;
        __builtin_amdgcn_global_load_lds((const AS1 void*)src,
                                         (AS3 void*)(lb + j * 4096 + tid * 16), 16, 0, 0);
      }
    }
    {
      char* lb = (char*)&Bs[0][0];
      #pragma unroll
      for (int j = 0; j < 4; j++){
        const ushort* src = Bg + (size_t)(colBase + j * 32 + rS) * (size_t)K + kc;
        __builtin_amdgcn_global_load_lds((const AS1 void*)src,
                                         (AS3 void*)(lb + j * 4096 + tid * 16), 16, 0, 0);
      }
    }
  };

  f16x8 av[4], bv[4];
  auto readKs = [&](int ks){
    int kc = (ks << 5) + lk;                    // 0..63
    #pragma unroll
    for (int n = 0; n < 4; n++)
      bv[n] = *(const f16x8*)&Bs[wc * 64 + n * 16 + lr][kc ^ swzR];
    #pragma unroll
    for (int m = 0; m < 4; m++)
      av[m] = *(const f16x8*)&As[wr * 64 + m * 16 + lr][kc ^ swzR];
  };

  f32x4 acc[4][4];
  #pragma unroll
  for (int m = 0; m < 4; m++)
    #pragma unroll
    for (int n = 0; n < 4; n++)
      acc[m][n] = (f32x4){0.f, 0.f, 0.f, 0.f};

  auto mfmaC = [&](){
    #pragma unroll
    for (int m = 0; m < 4; m++)
      #pragma unroll
      for (int n = 0; n < 4; n++)
        acc[m][n] = __builtin_amdgcn_mfma_f32_16x16x32_f16(av[m], bv[n], acc[m][n], 0, 0, 0);
  };

  // prologue
  stage(0);

  for (int t = 0; t < KB; ++t){
    asm volatile("s_waitcnt vmcnt(0)" ::: "memory");  // tile t landed
    SCHED0; SBAR; SCHED0;
    readKs(0);
    asm volatile("s_waitcnt lgkmcnt(0)" ::: "memory"); SCHED0;
    __builtin_amdgcn_s_setprio(1); mfmaC(); __builtin_amdgcn_s_setprio(0);
    SCHED0;
    readKs(1);
    asm volatile("s_waitcnt lgkmcnt(0)" ::: "memory"); SCHED0;
    SBAR; SCHED0;                                     // all reads done blockwide
    stage(t + 1); SCHED0;                             // DMA rides under MFMA
    __builtin_amdgcn_s_setprio(1); mfmaC(); __builtin_amdgcn_s_setprio(0);
    SCHED0;
  }
  asm volatile("s_waitcnt vmcnt(0)" ::: "memory");    // drain dead last stage

  // ---- epilogue ----
  // acc[m][n]: row = rowBase + wr*64 + m*16 + (lane>>4)*4 + r
  //            col = colBase + wc*64 + n*16 + lr
  if (sl.mode == 2){
    __syncthreads();
    #pragma unroll
    for (int m = 0; m < 4; m++){
      float p4[4] = {0.f, 0.f, 0.f, 0.f};
      #pragma unroll
      for (int n = 0; n < 4; n++){
        int col = colBase + wc * 64 + n * 16 + lr;
        float bv2 = sl.bias[col];
        float wv = sl.w3[col];
        #pragma unroll
        for (int r = 0; r < 4; r++)
          p4[r] += elu_f(acc[m][n][r] + bv2) * wv;
      }
      #pragma unroll
      for (int r = 0; r < 4; r++){
        #pragma unroll
        for (int s = 8; s > 0; s >>= 1) p4[r] += __shfl_xor(p4[r], s, 64);
      }
      if ((lane & 15) == 0){
        int hig = lane >> 4;
        int rowoff = wr * 64 + m * 16 + hig * 4;
        #pragma unroll
        for (int r = 0; r < 4; r++)
          red[wc][rowoff + r] = p4[r];
      }
    }
    __syncthreads();
    if (tid < 128){
      float s2 = red[0][tid] + red[1][tid];
      sl.ret[((size_t)bx * 8192 + rowBase + tid) * 8 + sl.eidx] = s2;  // bias in combine
    }
    return;
  }

  const int N = sl.N;
  #pragma unroll
  for (int m = 0; m < 4; m++){
    int row0 = rowBase + wr * 64 + m * 16 + ((lane >> 4) << 2);
    #pragma unroll
    for (int n = 0; n < 4; n++){
      int col = colBase + wc * 64 + n * 16 + lr;
      float bv2 = sl.bias[col];
      float v0 = elu_f(acc[m][n][0] + bv2);
      float v1 = elu_f(acc[m][n][1] + bv2);
      float v2 = elu_f(acc[m][n][2] + bv2);
      float v3 = elu_f(acc[m][n][3] + bv2);
      if (sl.mode == 0){
        ushort* C = (ushort*)sl.C;
        size_t r0b = (size_t)row0 * N + col;
        C[r0b]         = h2u((_Float16)v0);   // RN, not RTZ
        C[r0b + N]     = h2u((_Float16)v1);
        C[r0b + 2 * N] = h2u((_Float16)v2);
        C[r0b + 3 * N] = h2u((_Float16)v3);
      } else {
        float* C = (float*)sl.C;
        size_t r0b = (size_t)row0 * N + col;
        C[r0b]         = v0;
        C[r0b + N]     = v1;
        C[r0b + 2 * N] = v2;
        C[r0b + 3 * N] = v3;
      }
    }
  }
}

// ---- fused gate final layer + softmax + combine ----
__global__ void gate3_combine(const float* __restrict__ g2, const float* __restrict__ gw3,
                              const float* __restrict__ gb3, const float* __restrict__ ret2,
                              const float* __restrict__ eb3, float* __restrict__ out){
  int row = blockIdx.x * 4 + (threadIdx.x >> 6);
  int lane = threadIdx.x & 63;
  const float* g = g2 + (size_t)row * 256;
  float p[8];
  #pragma unroll
  for (int j = 0; j < 8; j++) p[j] = 0.f;
  for (int k = lane; k < 256; k += 64){
    float x = g[k];
    #pragma unroll
    for (int j = 0; j < 8; j++) p[j] += x * gw3[k * 8 + j];
  }
  #pragma unroll
  for (int j = 0; j < 8; j++){
    #pragma unroll
    for (int s = 32; s > 0; s >>= 1) p[j] += __shfl_xor(p[j], s, 64);
  }
  if (lane == 0){
    float mx = -1e30f;
    #pragma unroll
    for (int j = 0; j < 8; j++){ p[j] += gb3[j]; mx = fmaxf(mx, p[j]); }
    float sum = 0.f;
    #pragma unroll
    for (int j = 0; j < 8; j++){ p[j] = expf(p[j] - mx); sum += p[j]; }
    float inv = 1.f / sum;
    float s = 0.f;
    #pragma unroll
    for (int j = 0; j < 8; j++){
      float r = ret2[(size_t)row * 8 + j] + ret2[65536 + (size_t)row * 8 + j] + eb3[j];
      s += p[j] * inv * r;
    }
    out[row] = s;
  }
}

extern "C" void kernel_launch(void* const* d_in, const int* in_sizes, int n_in,
                              void* d_out, int out_size, void* d_ws, size_t ws_size,
                              hipStream_t stream){
  const float* obs  = (const float*)d_in[0];
  const float* code = (const float*)d_in[1];
  const float* ew0  = (const float*)d_in[2];
  const float* eb0  = (const float*)d_in[3];
  const float* ew1  = (const float*)d_in[4];
  const float* eb1  = (const float*)d_in[5];
  const float* ew2  = (const float*)d_in[6];
  const float* eb2  = (const float*)d_in[7];
  const float* ew3  = (const float*)d_in[8];
  const float* eb3  = (const float*)d_in[9];
  const float* gw0  = (const float*)d_in[10];
  const float* gb0  = (const float*)d_in[11];
  const float* gw1  = (const float*)d_in[12];
  const float* gb1  = (const float*)d_in[13];
  const float* gw2  = (const float*)d_in[14];
  const float* gb2  = (const float*)d_in[15];
  const float* gw3  = (const float*)d_in[16];
  const float* gb3  = (const float*)d_in[17];
  (void)in_sizes; (void)n_in; (void)out_size;

  char* ws = (char*)d_ws;
  size_t off = 0;
  auto alloc = [&](size_t bytes) -> void* {
    void* p = ws + off;
    off += (bytes + 255) & ~(size_t)255;
    return p;
  };
  ushort* A_obs  = (ushort*)alloc(8192ull * 512 * 2);      // [8192][512] f16
  ushort* A_code = (ushort*)alloc(8192ull * 64 * 2);       // [8192][64] f16
  ushort* B_ew0  = (ushort*)alloc(8ull * 1024 * 512 * 2);  // [8][1024][512] f16
  ushort* B_ew1  = (ushort*)alloc(8ull * 512 * 1024 * 2);
  ushort* B_ew2  = (ushort*)alloc(8ull * 256 * 512 * 2);
  ushort* B_gw0  = (ushort*)alloc(1024ull * 64 * 2);
  ushort* B_gw1  = (ushort*)alloc(512ull * 1024 * 2);
  ushort* B_gw2  = (ushort*)alloc(256ull * 512 * 2);
  float*  ret2   = (float*)alloc(2ull * 8192 * 8 * 4);
  const size_t fixed = off;

  const size_t sl0b = 8192ull * 1024 * 2;   // h0 single f16 (16.8MB)
  const size_t sl1b = 8192ull * 512 * 2;    // h1 single f16 (8.4MB)
  const size_t pairB = sl0b + sl1b;

  int G = 0;
  {
    const int cand[5] = {8, 4, 3, 2, 1};
    for (int ci = 0; ci < 5; ci++)
      if (fixed + (size_t)(cand[ci] + 1) * pairB <= ws_size){ G = cand[ci]; break; }
  }
  const bool gateFirst = (G == 0);
  const int ns = gateFirst ? 1 : (G + 1);
  ushort* h0buf = (ushort*)alloc((size_t)ns * sl0b);
  ushort* h1buf = (ushort*)alloc((size_t)ns * sl1b);
  const size_t sl0e = 8192ull * 1024;
  const size_t sl1e = 8192ull * 512;
  const int gsl = ns - 1;
  ushort* h0g = h0buf + (size_t)gsl * sl0e;
  ushort* h1g = h1buf + (size_t)gsl * sl1e;
  // h2 for the gate: G>=1 aliases the gate-slice h0 (experts never touch it);
  // gateFirst needs a dedicated buffer (combine reads it at the very end).
  float* h2g = gateFirst ? (float*)alloc(8192ull * 256 * 4) : (float*)h0g;

  // prep (2 dispatches)
  {
    AJob j0 = {obs,  A_obs,  8192 * 512};
    AJob j1 = {code, A_code, 8192 * 64};
    int t0 = 8192 * 512;
    prep_act_all<<<dim3((t0 + j1.total + 255) / 256), 256, 0, stream>>>(j0, j1, t0);

    WJobs wj; wj.njobs = 6;
    int bs = 0;
    auto addW = [&](int i, const float* W, ushort* Bt, int K, int N, int E){
      wj.j[i] = {W, Bt, K, N, N / 32, K / 32, bs};
      bs += E * (N / 32) * (K / 32);
    };
    addW(0, ew0, B_ew0, 512, 1024, 8);
    addW(1, ew1, B_ew1, 1024, 512, 8);
    addW(2, ew2, B_ew2, 512, 256, 8);
    addW(3, gw0, B_gw0, 64, 1024, 1);
    addW(4, gw1, B_gw1, 1024, 512, 1);
    addW(5, gw2, B_gw2, 512, 256, 1);
    prep_w_all<<<dim3(bs), dim3(32, 8), 0, stream>>>(wj);
  }

  // per-slice block counts at 128x128 tiles (gy = 64)
  const int NB0 = 8 * 64;    // L0: N=1024 -> 512
  const int NB1 = 4 * 64;    // L1: N=512  -> 256
  const int NB2 = 2 * 64;    // L2: N=256  -> 128

  auto runGroup = [&](int e0, int cnt, bool withGate){
    SliceArr sa; int nb;
    // L0
    nb = 0; sa.nz = cnt + (withGate ? 1 : 0);
    for (int i = 0; i < cnt; i++){ int e = e0 + i;
      sa.s[i] = {A_obs, B_ew0 + (size_t)e * 1024 * 512, eb0 + e * 1024,
                 h0buf + (size_t)i * sl0e, nullptr, nullptr, nullptr,
                 1024, 512, 3, 0, nb, 0};
      nb += NB0;
    }
    if (withGate){
      sa.s[cnt] = {A_code, B_gw0, gb0, h0g, nullptr, nullptr, nullptr,
                   1024, 64, 3, 0, nb, 0};
      nb += NB0;
    }
    for (int i = sa.nz; i < 9; i++) sa.s[i] = sa.s[0];
    gemm8p<<<dim3(nb), 256, 0, stream>>>(sa);
    // L1
    nb = 0;
    for (int i = 0; i < cnt; i++){ int e = e0 + i;
      sa.s[i] = {h0buf + (size_t)i * sl0e, B_ew1 + (size_t)e * 512 * 1024, eb1 + e * 512,
                 h1buf + (size_t)i * sl1e, nullptr, nullptr, nullptr,
                 512, 1024, 2, 0, nb, 0};
      nb += NB1;
    }
    if (withGate){
      sa.s[cnt] = {h0g, B_gw1, gb1, h1g, nullptr, nullptr, nullptr,
                   512, 1024, 2, 0, nb, 0};
      nb += NB1;
    }
    gemm8p<<<dim3(nb), 256, 0, stream>>>(sa);
    // L2: experts fused-returns partials (mode 2); gate f32 h2 (mode 1)
    nb = 0;
    for (int i = 0; i < cnt; i++){ int e = e0 + i;
      sa.s[i] = {h1buf + (size_t)i * sl1e, B_ew2 + (size_t)e * 256 * 512, eb2 + e * 256,
                 nullptr, ew3 + (size_t)e * 256, eb3 + e, ret2,
                 256, 512, 1, 2, nb, e};
      nb += NB2;
    }
    if (withGate){
      sa.s[cnt] = {h1g, B_gw2, gb2, h2g, nullptr, nullptr, nullptr,
                   256, 512, 1, 1, nb, 0};
      nb += NB2;
    }
    gemm8p<<<dim3(nb), 256, 0, stream>>>(sa);
  };

  if (gateFirst){
    SliceArr sa; sa.nz = 1;
    sa.s[0] = {A_code, B_gw0, gb0, h0g, nullptr, nullptr, nullptr, 1024, 64, 3, 0, 0, 0};
    for (int i = 1; i < 9; i++) sa.s[i] = sa.s[0];
    gemm8p<<<dim3(NB0), 256, 0, stream>>>(sa);
    sa.s[0] = {h0g, B_gw1, gb1, h1g, nullptr, nullptr, nullptr, 512, 1024, 2, 0, 0, 0};
    gemm8p<<<dim3(NB1), 256, 0, stream>>>(sa);
    sa.s[0] = {h1g, B_gw2, gb2, h2g, nullptr, nullptr, nullptr, 256, 512, 1, 1, 0, 0};
    gemm8p<<<dim3(NB2), 256, 0, stream>>>(sa);
    for (int e = 0; e < 8; e++) runGroup(e, 1, false);
  } else {
    bool first = true;
    for (int e0 = 0; e0 < 8; ){
      int cnt = (8 - e0 < G) ? (8 - e0) : G;
      runGroup(e0, cnt, first);
      first = false;
      e0 += cnt;
    }
  }

  gate3_combine<<<dim3(2048), 256, 0, stream>>>(h2g, gw3, gb3, ret2, eb3, (float*)d_out);
}